// Round 13
// baseline (158.003 us; speedup 1.0000x reference)
//
#include <hip/hip_runtime.h>

// R27 = best-known passing kernel (R25 body, R20 pkrelu). FINAL STRUCTURE.
// R26 post-mortem: v_pk_max_i16 packed ReLU FAILED (absmax 0.043) despite a
// sound paper proof — second packed-ReLU failure (R22 pk_max_f16: NaN),
// mechanism not isolatable blind; line of attack permanently dead.
// Plateau accounting: per-CU demands MFMA 39us / LDS 41us / VALU 32us;
// wall 86us (~25% overlap). TLP provably capped at 4 waves/SIMD (live set
// ~56 VGPR can never fit the <=42/<=32 tiers 6/8 waves need, any variant).
// ILP levers measured null/negative: manual pipeline -12%, setprio null,
// stagger null, 32x32 shape spills at the forced 64-reg ceiling, LDS-extras
// -8%. Demand lever taken: cvt_pk (-10%, R20). Floor = max(demand) ~41us/CU
// unreachable within this structure.
//
// ws layout (bytes) — written by nerf_stage (same as R12..R26):
//   0     : W2 frags, 32 x 1024   (f = ks*8+nt; lane l at f*1024 + l*16)
//   32768 : W3 frags, 32 x 1024
//   65536 : L1 compact, 8 x 256   (frag nt, slot n: j<6 -> W1[(nt*16+n)*6+j],
//                                  j==6 -> b1[nt*16+n], j==7 -> 0)
//   67584 : L4 compact, 4 x 256   (frag ks, slot s=q*4+outrow)
//   68608 : zeros, 2048
//   70656 : bias2 = b2[0..127]    (f32x4 entry nt*4+q)
//   71168 : bias3 = b3[0..127]
//   71680 : b4 padded (q==0 -> b4[0..3], else 0)

typedef __attribute__((ext_vector_type(8))) short short8;
typedef __attribute__((ext_vector_type(4))) float f32x4;
typedef __attribute__((ext_vector_type(2))) float f32x2;
typedef __attribute__((ext_vector_type(4))) unsigned int u32x4;

#define MFMA(a, b, c) __builtin_amdgcn_mfma_f32_16x16x32_bf16((a), (b), (c), 0, 0, 0)

__device__ __forceinline__ unsigned short bfr(float f) {  // fp32->bf16 RNE
  unsigned u = __builtin_bit_cast(unsigned, f);
  u += 0x7FFFu + ((u >> 16) & 1u);
  return (unsigned short)(u >> 16);
}

// (bf16(a) low16, bf16(b) high16) in ONE v_cvt_pk_bf16_f32 (R20's win).
__device__ __forceinline__ unsigned pk2(float a, float b) {
  unsigned r;
  asm("v_cvt_pk_bf16_f32 %0, %1, %2" : "=v"(r) : "v"(a), "v"(b));
  return r;
}

// PROVEN pkrelu: 2x fmax + 1x cvt_pk. (Packed-max variants failed on HW
// twice — R22 f16: NaN, R26 i16: absmax 0.043. Do not retry.)
__device__ __forceinline__ unsigned pkrelu(float a, float b) {
  a = __builtin_fmaxf(a, 0.f);
  b = __builtin_fmaxf(b, 0.f);
  return pk2(a, b);
}

__device__ __forceinline__ short8 pack4(const f32x4& a0, const f32x4& a1) {
  u32x4 u;
  u.x = pkrelu(a0.x, a0.y);
  u.y = pkrelu(a0.z, a0.w);
  u.z = pkrelu(a1.x, a1.y);
  u.w = pkrelu(a1.z, a1.w);
  return __builtin_bit_cast(short8, u);
}

// consumer B k-slot kp <- producer neuron slot sig_inv(kp)
__device__ __forceinline__ int sig_inv(int kp) {
  return ((kp >> 5) << 5) + (((kp >> 2) & 1) << 4) + (((kp >> 3) & 3) << 2) + (kp & 3);
}

__global__ void nerf_stage(const float* __restrict__ W1, const float* __restrict__ b1,
                           const float* __restrict__ W2, const float* __restrict__ b2,
                           const float* __restrict__ W3, const float* __restrict__ b3,
                           const float* __restrict__ W4, const float* __restrict__ b4,
                           void* __restrict__ ws) {
  unsigned short* wf = (unsigned short*)ws;
  const int idx = blockIdx.x * 256 + threadIdx.x;
  const int stride = gridDim.x * 256;

  // W2 (f 0..31) and W3 (f 32..63) full frags
  for (int p = idx; p < 64 * 64; p += stride) {
    const int f = p >> 6, l = p & 63, m = l & 15, q = l >> 4;
    const int g = f & 31, ks = g >> 3, nt = g & 7;
    const float* W = (f < 32) ? W2 : W3;
    unsigned short v[8];
#pragma unroll
    for (int j = 0; j < 8; ++j)
      v[j] = bfr(W[(nt * 16 + m) * 128 + sig_inv(ks * 32 + q * 8 + j)]);
#pragma unroll
    for (int j = 0; j < 8; ++j) wf[f * 512 + l * 8 + j] = v[j];
  }

  // L1 compact: 8 frags x 16 slots at byte 65536
  for (int e = idx; e < 128; e += stride) {
    const int nt = e >> 4, n = e & 15;
    unsigned short v[8];
#pragma unroll
    for (int j = 0; j < 8; ++j) {
      float val = 0.f;
      if (j < 6) val = W1[(nt * 16 + n) * 6 + j];
      else if (j == 6) val = b1[nt * 16 + n];
      v[j] = bfr(val);
    }
#pragma unroll
    for (int j = 0; j < 8; ++j) wf[(65536 >> 1) + e * 8 + j] = v[j];
  }

  // L4 compact: 4 frags x 16 slots (s = q*4 + outrow) at byte 67584
  for (int e = idx; e < 64; e += stride) {
    const int ks = e >> 4, s = e & 15, q = s >> 2, n = s & 3;
    unsigned short v[8];
#pragma unroll
    for (int j = 0; j < 8; ++j)
      v[j] = bfr(W4[n * 128 + sig_inv(ks * 32 + q * 8 + j)]);
#pragma unroll
    for (int j = 0; j < 8; ++j) wf[(67584 >> 1) + e * 8 + j] = v[j];
  }

  // zeros at byte 68608 (ws is poisoned 0xAA each launch -> must clear)
  {
    float* z = (float*)((char*)ws + 68608);
    for (int e = idx; e < 512; e += stride) z[e] = 0.f;
  }

  // biases at byte 70656: b2 | b3 | b4 padded
  {
    float* wb = (float*)((char*)ws + 70656);
    for (int e = idx; e < 272; e += stride) {
      float val;
      if (e < 128) val = b2[e];
      else if (e < 256) val = b3[e - 128];
      else val = ((e & 15) < 4) ? b4[e & 3] : 0.f;
      wb[e] = val;
    }
  }
}

__launch_bounds__(1024, 4)
__global__ void nerf_main(const float* __restrict__ x, float* __restrict__ out,
                          const void* __restrict__ ws, int nGroups) {
  __shared__ __align__(16) unsigned short lds[32768];  // exactly 65536 B: W2 | W3

  {  // copy W2/W3 frags only: 65536/16 = 4096 16B chunks
    const u32x4* src = (const u32x4*)ws;
    u32x4* dst = (u32x4*)lds;
    for (int i = threadIdx.x; i < 4096; i += 1024) dst[i] = src[i];
  }
  __syncthreads();

  const int lane = threadIdx.x & 63;
  const int wid = threadIdx.x >> 6;  // 0..15
  const int q = lane >> 4;
  const int n = lane & 15;

  // ---- phase stagger (null-to-noise, harmless; one-time <=1536 cyc) ----
  {
    const int ws4 = wid & 3;
    if (ws4 == 1) __builtin_amdgcn_s_sleep(8);        // ~512 cyc
    else if (ws4 == 2) __builtin_amdgcn_s_sleep(16);  // ~1024 cyc
    else if (ws4 == 3) __builtin_amdgcn_s_sleep(24);  // ~1536 cyc
  }

  const int waveId = blockIdx.x * 16 + wid;
  const int totalWaves = gridDim.x * 16;

  // LDS bases (frag index in the offset)
  const unsigned short* w2b = lds + lane * 8;            // + (ks*8+nt)*512
  const unsigned short* w3b = lds + 16384 + lane * 8;    // + (ks*8+nt)*512

  // lane-conditional byte offsets for the extras (bases derived per-iteration
  // from the laundered pointer so the loads cannot be hoisted out of the loop)
  const int l1off = ((q == 0) ? 65536 : 68608) + n * 16;
  const int l4off = (n < 4) ? (67584 + (q * 4 + n) * 16) : (68608 + n * 16);
  const int b2off = 70656 + q * 16;
  const int b3off = 71168 + q * 16;
  const int b4off = 71680 + q * 16;

  const f32x4 zf = {0.f, 0.f, 0.f, 0.f};

  float px[2][6] = {};
  int g = waveId;
  if (g < nGroups && q == 0) {
#pragma unroll
    for (int t = 0; t < 2; ++t) {
      const float* p = x + (g * 32 + t * 16 + n) * 6;
      f32x2 a = *(const f32x2*)p, b = *(const f32x2*)(p + 2), c = *(const f32x2*)(p + 4);
      px[t][0] = a.x; px[t][1] = a.y; px[t][2] = b.x;
      px[t][3] = b.y; px[t][4] = c.x; px[t][5] = c.y;
    }
  }

  for (; g < nGroups; g += totalWaves) {
    // ---- anti-hoist: launder the extras base every iteration ----
    uintptr_t wsl = (uintptr_t)ws;
    asm volatile("" : "+v"(wsl));  // opaque -> extras loads stay in the loop
    const char* wsv = (const char*)wsl;
    const short8* l1g = (const short8*)(wsv + l1off);   // + nt*16
    const short8* l4g = (const short8*)(wsv + l4off);   // + ks*16
    const f32x4* bias2 = (const f32x4*)(wsv + b2off);   // + nt*4
    const f32x4* bias3 = (const f32x4*)(wsv + b3off);   // + nt*4
    const f32x4* b4p   = (const f32x4*)(wsv + b4off);

    // ---- x -> layer-1 B frags (q==0: k0..5 = x, k6 = 1.0 bias slot) ----
    short8 xb[2];
#pragma unroll
    for (int t = 0; t < 2; ++t) {
      u32x4 u = {0u, 0u, 0u, 0u};
      if (q == 0) {
        u.x = pk2(px[t][0], px[t][1]);
        u.y = pk2(px[t][2], px[t][3]);
        u.z = pk2(px[t][4], px[t][5]);
        u.w = 0x00003F80u;  // elem6 = bf16 1.0, elem7 = 0
      }
      xb[t] = __builtin_bit_cast(short8, u);
    }
    const int gn = g + totalWaves;
    if (gn < nGroups && q == 0) {
#pragma unroll
      for (int t = 0; t < 2; ++t) {
        const float* p = x + (gn * 32 + t * 16 + n) * 6;
        f32x2 a = *(const f32x2*)p, b = *(const f32x2*)(p + 2), c = *(const f32x2*)(p + 4);
        px[t][0] = a.x; px[t][1] = a.y; px[t][2] = b.x;
        px[t][3] = b.y; px[t][4] = c.x; px[t][5] = c.y;
      }
    }

    short8 B1[2][4], B2[2][4];

    // ---- layer 1 (compact frags from global/L2; bias in k-slot 6; C=0) ----
#pragma unroll
    for (int ntp = 0; ntp < 4; ++ntp) {
      const short8 w0 = l1g[(2 * ntp) * 16];
      const short8 w1 = l1g[(2 * ntp + 1) * 16];
      f32x4 a0[2], a1[2];
      __builtin_amdgcn_s_setprio(1);
#pragma unroll
      for (int t = 0; t < 2; ++t) {
        a0[t] = MFMA(w0, xb[t], zf);
        a1[t] = MFMA(w1, xb[t], zf);
      }
      __builtin_amdgcn_s_setprio(0);
#pragma unroll
      for (int t = 0; t < 2; ++t) B1[t][ntp] = pack4(a0[t], a1[t]);
    }

    // ---- layer 2 (W2 frags from LDS; bias as C at ks==0) ----
#pragma unroll
    for (int ntp = 0; ntp < 4; ++ntp) {
      f32x4 a0[2], a1[2];
      __builtin_amdgcn_s_setprio(1);
#pragma unroll
      for (int ks = 0; ks < 4; ++ks) {
        const short8 w0 = *(const short8*)(w2b + (ks * 8 + 2 * ntp) * 512);
        const short8 w1 = *(const short8*)(w2b + (ks * 8 + 2 * ntp + 1) * 512);
        if (ks == 0) {
          const f32x4 bv0 = bias2[(2 * ntp) * 4];
          const f32x4 bv1 = bias2[(2 * ntp + 1) * 4];
#pragma unroll
          for (int t = 0; t < 2; ++t) {
            a0[t] = MFMA(w0, B1[t][0], bv0);
            a1[t] = MFMA(w1, B1[t][0], bv1);
          }
        } else {
#pragma unroll
          for (int t = 0; t < 2; ++t) {
            a0[t] = MFMA(w0, B1[t][ks], a0[t]);
            a1[t] = MFMA(w1, B1[t][ks], a1[t]);
          }
        }
      }
      __builtin_amdgcn_s_setprio(0);
#pragma unroll
      for (int t = 0; t < 2; ++t) B2[t][ntp] = pack4(a0[t], a1[t]);
    }

    // ---- layer 3 (W3 frags from LDS) ----
#pragma unroll
    for (int ntp = 0; ntp < 4; ++ntp) {
      f32x4 a0[2], a1[2];
      __builtin_amdgcn_s_setprio(1);
#pragma unroll
      for (int ks = 0; ks < 4; ++ks) {
        const short8 w0 = *(const short8*)(w3b + (ks * 8 + 2 * ntp) * 512);
        const short8 w1 = *(const short8*)(w3b + (ks * 8 + 2 * ntp + 1) * 512);
        if (ks == 0) {
          const f32x4 bv0 = bias3[(2 * ntp) * 4];
          const f32x4 bv1 = bias3[(2 * ntp + 1) * 4];
#pragma unroll
          for (int t = 0; t < 2; ++t) {
            a0[t] = MFMA(w0, B2[t][0], bv0);
            a1[t] = MFMA(w1, B2[t][0], bv1);
          }
        } else {
#pragma unroll
          for (int t = 0; t < 2; ++t) {
            a0[t] = MFMA(w0, B2[t][ks], a0[t]);
            a1[t] = MFMA(w1, B2[t][ks], a1[t]);
          }
        }
      }
      __builtin_amdgcn_s_setprio(0);
#pragma unroll
      for (int t = 0; t < 2; ++t) B1[t][ntp] = pack4(a0[t], a1[t]);  // reuse B1
    }

    // ---- layer 4 (compact frags from global/L2; out rows at q==0) ----
    f32x4 o[2];
    {
      const f32x4 bv = b4p[0];
      __builtin_amdgcn_s_setprio(1);
#pragma unroll
      for (int ks = 0; ks < 4; ++ks) {
        const short8 w = l4g[ks * 16];
        if (ks == 0) {
#pragma unroll
          for (int t = 0; t < 2; ++t) o[t] = MFMA(w, B1[t][0], bv);
        } else {
#pragma unroll
          for (int t = 0; t < 2; ++t) o[t] = MFMA(w, B1[t][ks], o[t]);
        }
      }
      __builtin_amdgcn_s_setprio(0);
    }
    if (q == 0) {
#pragma unroll
      for (int t = 0; t < 2; ++t)
        *(f32x4*)(out + (g * 32 + t * 16 + n) * 4) = o[t];
    }
  }
}

extern "C" void kernel_launch(void* const* d_in, const int* in_sizes, int n_in,
                              void* d_out, int out_size, void* d_ws, size_t ws_size,
                              hipStream_t stream) {
  const float* x  = (const float*)d_in[0];
  const float* W1 = (const float*)d_in[1];
  const float* b1 = (const float*)d_in[2];
  const float* W2 = (const float*)d_in[3];
  const float* b2 = (const float*)d_in[4];
  const float* W3 = (const float*)d_in[5];
  const float* b3 = (const float*)d_in[6];
  const float* W4 = (const float*)d_in[7];
  const float* b4 = (const float*)d_in[8];
  float* out = (float*)d_out;

  const int N = in_sizes[0] / 6;
  const int nGroups = N / 32;  // 2 tiles of 16 rows per wave-iteration -> 32768

  nerf_stage<<<dim3(32), dim3(256), 0, stream>>>(W1, b1, W2, b2, W3, b3, W4, b4, d_ws);

  // 512 blocks x 16 waves; regs cap residency at 16 waves/CU (4/SIMD).
  nerf_main<<<dim3(512), dim3(1024), 0, stream>>>(x, out, d_ws, nGroups);
}